// Round 3
// baseline (1626.087 us; speedup 1.0000x reference)
//
#include <hip/hip_runtime.h>
#include <cstdint>
#include <cstddef>

typedef _Float16 f16;
typedef __attribute__((ext_vector_type(8))) _Float16 half8;
typedef __attribute__((ext_vector_type(4))) _Float16 half4;
typedef __attribute__((ext_vector_type(8))) short short8;
typedef __attribute__((ext_vector_type(4))) float floatx4;
typedef __attribute__((ext_vector_type(8))) float floatx8;

__device__ __forceinline__ float rcp_(float x) { return __builtin_amdgcn_rcpf(x); }
__device__ __forceinline__ float sigm(float x) { return rcp_(1.f + __expf(-x)); }
__device__ __forceinline__ float tanh_(float x) { return 1.f - 2.f * rcp_(1.f + __expf(2.f * x)); }

// Dual-job 128x128-tile GEMM: C[M,N] = A[M,256] @ BT[N,256]^T, fp16 in/out,
// fp32 accum. (Only used once, for the 32000x1024 vocab table.)
__global__ __launch_bounds__(256) void gemm128d(
    const f16* __restrict__ A0, const f16* __restrict__ B0, f16* __restrict__ C0,
    int ldc0, int nt0, int tiles0,
    const f16* __restrict__ A1, const f16* __restrict__ B1, f16* __restrict__ C1,
    int ldc1, int nt1)
{
  const f16* A; const f16* BT; f16* C; int ldc_, mi, ni;
  int bid = blockIdx.x;
  if (bid < tiles0) { A = A0; BT = B0; C = C0; ldc_ = ldc0; mi = bid / nt0; ni = bid % nt0; }
  else { int r = bid - tiles0; A = A1; BT = B1; C = C1; ldc_ = ldc1; mi = r / nt1; ni = r % nt1; }
  const int m0 = mi * 128;
  const int n0 = ni * 128;

  __shared__ short lA[128 * 72];
  __shared__ short lB[128 * 72];
  const int t = threadIdx.x;
  const int wave = t >> 6;
  const int lane = t & 63;
  const int ln = lane & 15;
  const int quad = lane >> 4;
  const int wr = wave >> 1;
  const int wc = wave & 1;

  floatx4 acc[4][4];
#pragma unroll
  for (int i = 0; i < 4; ++i)
#pragma unroll
    for (int j = 0; j < 4; ++j) acc[i][j] = (floatx4){0.f, 0.f, 0.f, 0.f};

#pragma unroll
  for (int st = 0; st < 4; ++st) {    // K = 256 in 4 stages of 64
    const int k0 = st * 64;
#pragma unroll
    for (int i = 0; i < 4; ++i) {     // 128 rows x 8 chunks of 8 halves
      int chunk = t + 256 * i;
      int row = chunk >> 3;
      int cc = chunk & 7;
      *(short8*)&lA[row * 72 + cc * 8] =
          *(const short8*)(A + (size_t)(m0 + row) * 256 + k0 + cc * 8);
      *(short8*)&lB[row * 72 + cc * 8] =
          *(const short8*)(BT + (size_t)(n0 + row) * 256 + k0 + cc * 8);
    }
    __syncthreads();
#pragma unroll
    for (int ks = 0; ks < 2; ++ks) {
      const int kk = ks * 32 + quad * 8;
      half8 a[4], b[4];
#pragma unroll
      for (int rf = 0; rf < 4; ++rf)
        a[rf] = __builtin_bit_cast(half8,
            *(const short8*)&lA[(wr * 64 + rf * 16 + ln) * 72 + kk]);
#pragma unroll
      for (int cf = 0; cf < 4; ++cf)
        b[cf] = __builtin_bit_cast(half8,
            *(const short8*)&lB[(wc * 64 + cf * 16 + ln) * 72 + kk]);
#pragma unroll
      for (int rf = 0; rf < 4; ++rf)
#pragma unroll
        for (int cf = 0; cf < 4; ++cf)
          acc[rf][cf] = __builtin_amdgcn_mfma_f32_16x16x32_f16(
              a[rf], b[cf], acc[rf][cf], 0, 0, 0);
    }
    __syncthreads();
  }
#pragma unroll
  for (int rf = 0; rf < 4; ++rf)
#pragma unroll
    for (int cf = 0; cf < 4; ++cf)
#pragma unroll
      for (int r = 0; r < 4; ++r) {
        int row = m0 + wr * 64 + rf * 16 + quad * 4 + r;
        int col = n0 + wc * 64 + cf * 16 + ln;
        C[(size_t)row * ldc_ + col] = (f16)acc[rf][cf][r];
      }
}

// fp32 inputs -> fp16 working copies; also zeroes the grid-barrier counters.
__global__ __launch_bounds__(256) void prep(
    const float* __restrict__ emb, const float* __restrict__ Wioux,
    const float* __restrict__ Wfx, const float* __restrict__ Wiouh,
    const float* __restrict__ Wfh,
    f16* __restrict__ emb_h, f16* __restrict__ BTX,
    f16* __restrict__ WiouhT, f16* __restrict__ WfhT,
    int* __restrict__ ctr)
{
  int idx = blockIdx.x * 256 + threadIdx.x;   // 10049 blocks = 2,572,544
  if (idx < 8) ctr[idx] = 0;                  // grid-barrier counters
  if (idx < 2048000) {                        // emb: 4 elems/thread
    floatx4 v = *(const floatx4*)(emb + 4 * (size_t)idx);
    half4 o;
#pragma unroll
    for (int j = 0; j < 4; ++j) o[j] = (f16)v[j];
    *(half4*)(emb_h + 4 * (size_t)idx) = o;
  } else if (idx < 2310144) {
    int r = idx - 2048000;                    // BTX[1024,256]: Wioux^T | Wfx^T
    int j = r >> 8, k = r & 255;
    BTX[r] = (f16)((j < 768) ? Wioux[(size_t)k * 768 + j]
                             : Wfx[(size_t)k * 256 + (j - 768)]);
  } else if (idx < 2506752) {
    int r = idx - 2310144;                    // WiouhT[768,256]
    int j = r >> 8, k = r & 255;
    WiouhT[r] = (f16)Wiouh[(size_t)k * 768 + j];
  } else {
    int r = idx - 2506752;                    // WfhT[256,256]
    int j = r >> 8, k = r & 255;
    WfhT[r] = (f16)Wfh[(size_t)k * 256 + j];
  }
}

// Leaf elementwise: block = 8 nodes; gates -> c16/h/h16; parent hsum16 via LDS.
__global__ __launch_bounds__(256) void elem8(
    const int* __restrict__ tokens, const f16* __restrict__ TIOUF,
    const float* __restrict__ bioux, const float* __restrict__ biouh,
    f16* __restrict__ c16, float* __restrict__ h, f16* __restrict__ h16,
    f16* __restrict__ hsum16, int s, int sz, int s_up, int sz_up)
{
  __shared__ float hsh[8 * 260];
  const int t = threadIdx.x;
  const int nloc = t >> 5;
  const int d0 = (t & 31) * 8;
  const int base = s + 8 * blockIdx.x;
  const int node = base + nloc;
  const int lim = s + sz;

  if (node < lim) {
    const f16* ti = TIOUF + (size_t)tokens[node] * 1024;
    half8 t0 = *(const half8*)(ti + d0);
    half8 t1 = *(const half8*)(ti + 256 + d0);
    half8 t2 = *(const half8*)(ti + 512 + d0);
    floatx8 bi0 = *(const floatx8*)(bioux + d0) + *(const floatx8*)(biouh + d0);
    floatx8 bi1 = *(const floatx8*)(bioux + 256 + d0) + *(const floatx8*)(biouh + 256 + d0);
    floatx8 bi2 = *(const floatx8*)(bioux + 512 + d0) + *(const floatx8*)(biouh + 512 + d0);

    float cv[8];
#pragma unroll
    for (int j = 0; j < 8; ++j)
      cv[j] = sigm((float)t0[j] + bi0[j]) * tanh_((float)t2[j] + bi2[j]);

    half8 c8, h8;
    floatx8 hf;
#pragma unroll
    for (int j = 0; j < 8; ++j) {
      float hv = sigm((float)t1[j] + bi1[j]) * tanh_(cv[j]);
      c8[j] = (f16)cv[j];
      h8[j] = (f16)hv;
      hf[j] = hv;
    }
    *(half8*)(c16 + (size_t)node * 256 + d0) = c8;
    *(floatx8*)(h + (size_t)node * 256 + d0) = hf;
    *(half8*)(h16 + (size_t)node * 256 + d0) = h8;
    *(floatx8*)&hsh[nloc * 260 + d0] = hf;
  }
  __syncthreads();

  if (t < 64) {
    int p = t >> 5;
    int dd = (t & 31) * 8;
    int parent = ((base - 1) >> 2) + p;
    if (parent < s_up + sz_up) {
      floatx8 v = *(const floatx8*)&hsh[(4 * p + 0) * 260 + dd] +
                  *(const floatx8*)&hsh[(4 * p + 1) * 260 + dd] +
                  *(const floatx8*)&hsh[(4 * p + 2) * 260 + dd] +
                  *(const floatx8*)&hsh[(4 * p + 3) * 260 + dd];
      half8 o;
#pragma unroll
      for (int j = 0; j < 8; ++j) o[j] = (f16)v[j];
      *(half8*)(hsum16 + (size_t)(parent - s_up) * 256 + dd) = o;
    }
  }
}

// One 16-parent x 128-dim tile of an internal level: dual in-register GEMM
// (IOUH via hsum_in @ WiouhT, FH via children h16 @ WfhT) + gates + stores.
// LDS: lA = 80 rows x 256 shorts, XOR-swizzled (chunk ^= row&7) so total LDS
// is exactly 40960 B -> 4 blocks/CU at 512 thr. lFS overlays dead lA after
// the K-loop barrier (wave-private, lgkmcnt-fenced).
// MFMA C layout: row-in-tile = 4*quad + reg, col = lane&15.
__device__ __forceinline__ void do_tile(
    short* lA,
    const int* __restrict__ tokens, const f16* __restrict__ TIOUF,
    const f16* __restrict__ WiouhT, const f16* __restrict__ WfhT,
    const float* __restrict__ bioux, const float* __restrict__ biouh,
    const float* __restrict__ bfx, const float* __restrict__ bfh,
    f16* __restrict__ c16, float* __restrict__ h, f16* __restrict__ h16,
    const f16* __restrict__ hsum_in, f16* __restrict__ hsum_out,
    int s, int sz, int sz_up, int pt, int pg)
{
  const int t = threadIdx.x;
  const int p0 = s + pt * 16;        // first parent of tile
  const int c0 = 4 * p0 + 1;         // first child node (contiguous 64 rows)

  // stage A: rows 0-15 hsum(parents), 16-79 children h16; swizzled chunks
#pragma unroll
  for (int i = 0; i < 5; ++i) {
    int chunk = t + 512 * i;
    int row = chunk >> 5;
    int cc = chunk & 31;
    const f16* src = (row < 16)
        ? hsum_in + (size_t)(pt * 16 + row) * 256 + cc * 8
        : h16 + (size_t)(c0 + row - 16) * 256 + cc * 8;
    *(short8*)&lA[row * 256 + (cc ^ (row & 7)) * 8] = *(const short8*)src;
  }
  __syncthreads();

  const int wave = t >> 6;
  const int lane = t & 63;
  const int ln = lane & 15;
  const int q = lane >> 4;
  const int rb = ln & 7;
  const int dim = (pg * 8 + wave) * 16 + ln;   // 0..255

  floatx4 accI[3], accF[4];
#pragma unroll
  for (int i = 0; i < 3; ++i) accI[i] = (floatx4){0.f, 0.f, 0.f, 0.f};
#pragma unroll
  for (int i = 0; i < 4; ++i) accF[i] = (floatx4){0.f, 0.f, 0.f, 0.f};

  const short* aBase = &lA[ln * 256];
  const f16* b0p = WiouhT + (size_t)dim * 256 + 8 * q;
  const f16* b1p = b0p + 256 * 256;
  const f16* b2p = b0p + 512 * 256;
  const f16* bfp = WfhT + (size_t)dim * 256 + 8 * q;

#pragma unroll
  for (int ks = 0; ks < 8; ++ks) {   // K = 256 in 8 steps of 32
    const int ko = 32 * ks;
    const int co = ((q + 4 * ks) ^ rb) * 8;    // swizzled chunk offset
    half8 ah = __builtin_bit_cast(half8, *(const short8*)(aBase + co));
    half8 b0 = *(const half8*)(b0p + ko);
    half8 b1 = *(const half8*)(b1p + ko);
    half8 b2 = *(const half8*)(b2p + ko);
    half8 bf = *(const half8*)(bfp + ko);
    accI[0] = __builtin_amdgcn_mfma_f32_16x16x32_f16(ah, b0, accI[0], 0, 0, 0);
    accI[1] = __builtin_amdgcn_mfma_f32_16x16x32_f16(ah, b1, accI[1], 0, 0, 0);
    accI[2] = __builtin_amdgcn_mfma_f32_16x16x32_f16(ah, b2, accI[2], 0, 0, 0);
#pragma unroll
    for (int rt = 0; rt < 4; ++rt) {
      half8 ac = __builtin_bit_cast(half8,
          *(const short8*)(aBase + (16 + 16 * rt) * 256 + co));
      accF[rt] = __builtin_amdgcn_mfma_f32_16x16x32_f16(ac, bf, accF[rt], 0, 0, 0);
    }
  }
  __syncthreads();                   // all waves done with lA; overlay lFS

  float* myFS = (float*)lA + wave * (16 * 17);   // wave-private 16x17 f32

  const float bi0 = bioux[dim] + biouh[dim];
  const float bi1 = bioux[256 + dim] + biouh[256 + dim];
  const float bi2 = bioux[512 + dim] + biouh[512 + dim];
  const float bff = bfx[dim] + bfh[dim];

  // f-gates in FH layout: tile rt, reg r -> child (16rt+4q+r) of parent 4rt+q
#pragma unroll
  for (int rt = 0; rt < 4; ++rt) {
    int po = 4 * rt + q;
    int tok = tokens[p0 + po];
    float xff = (float)TIOUF[(size_t)tok * 1024 + 768 + dim] + bff;
    float fs = 0.f;
#pragma unroll
    for (int r = 0; r < 4; ++r)
      fs += sigm(accF[rt][r] + xff) *
            (float)c16[(size_t)(c0 + 16 * rt + 4 * q + r) * 256 + dim];
    myFS[po * 17 + ln] = fs;
  }
  // write->read is same-wave only: drain LDS writes, pin the order
  asm volatile("s_waitcnt lgkmcnt(0)" ::: "memory");
  __builtin_amdgcn_sched_barrier(0);

  const int szrem = sz - pt * 16;
  float hsum = 0.f;
#pragma unroll
  for (int r = 0; r < 4; ++r) {      // IOUH layout: reg r -> parent 4q+r
    int po = 4 * q + r;
    const f16* tp = TIOUF + (size_t)tokens[p0 + po] * 1024;
    float iv = sigm(accI[0][r] + (float)tp[dim] + bi0);
    float ov = sigm(accI[1][r] + (float)tp[256 + dim] + bi1);
    float uv = tanh_(accI[2][r] + (float)tp[512 + dim] + bi2);
    float cn = iv * uv + myFS[po * 17 + ln];
    float hn = ov * tanh_(cn);
    hsum += hn;                      // 4 regs = 4 siblings => in-lane hsum
    if (po < szrem) {                // guard tail tiles (stores only)
      size_t pi = (size_t)(p0 + po);
      c16[pi * 256 + dim] = (f16)cn;
      h16[pi * 256 + dim] = (f16)hn;
      h[pi * 256 + dim] = hn;
    }
  }
  if (sz_up > 0) {
    int g_row = 4 * pt + q;          // next-level relative parent row
    if (g_row < sz_up)
      hsum_out[(size_t)g_row * 256 + dim] = (f16)hsum;
  }
}

// Level 1 (16384 parents): plain launch, 2048 blocks, 4 blocks/CU.
__global__ __launch_bounds__(512, 8) void fused_level(
    const int* __restrict__ tokens, const f16* __restrict__ TIOUF,
    const f16* __restrict__ WiouhT, const f16* __restrict__ WfhT,
    const float* __restrict__ bioux, const float* __restrict__ biouh,
    const float* __restrict__ bfx, const float* __restrict__ bfh,
    f16* __restrict__ c16, float* __restrict__ h, f16* __restrict__ h16,
    const f16* __restrict__ hsum_in, f16* __restrict__ hsum_out,
    int s, int sz, int sz_up)
{
  __shared__ short lA[80 * 256];     // 40960 B exactly
  do_tile(lA, tokens, TIOUF, WiouhT, WfhT, bioux, biouh, bfx, bfh,
          c16, h, h16, hsum_in, hsum_out, s, sz, sz_up,
          blockIdx.x >> 1, blockIdx.x & 1);
}

// Levels 2..8 in ONE kernel. grid = 512 blocks; __launch_bounds__(512,4)
// (VGPR<=128) + 40 KB LDS guarantee >=2 blocks/CU -> all 512 co-resident,
// so the device-scope spin barrier between levels cannot deadlock.
__global__ __launch_bounds__(512, 4) void multi_level(
    const int* __restrict__ tokens, const f16* __restrict__ TIOUF,
    const f16* __restrict__ WiouhT, const f16* __restrict__ WfhT,
    const float* __restrict__ bioux, const float* __restrict__ biouh,
    const float* __restrict__ bfx, const float* __restrict__ bfh,
    f16* __restrict__ c16, float* __restrict__ h, f16* __restrict__ h16,
    f16* __restrict__ hsumA, f16* __restrict__ hsumB, int* __restrict__ ctr)
{
  __shared__ short lA[80 * 256];
  const int t = threadIdx.x;
  // levels i=2..8: {s, sz, sz_up}
#pragma unroll
  for (int l = 0; l < 7; ++l) {
    const int Ls  = (l == 0) ? 1365 : (l == 1) ? 341 : (l == 2) ? 85
                  : (l == 3) ? 21 : (l == 4) ? 5 : (l == 5) ? 1 : 0;
    const int Lsz = (l == 0) ? 4096 : (l == 1) ? 1024 : (l == 2) ? 256
                  : (l == 3) ? 64 : (l == 4) ? 16 : (l == 5) ? 4 : 1;
    const int Lup = (l == 0) ? 1024 : (l == 1) ? 256 : (l == 2) ? 64
                  : (l == 3) ? 16 : (l == 4) ? 4 : (l == 5) ? 1 : 0;
    const f16* hin = (l & 1) ? hsumA : hsumB;   // L1 wrote hsumB; alternate
    f16* hout = (l & 1) ? hsumB : hsumA;
    int ntb = 2 * ((Lsz + 15) / 16);
    for (int b = blockIdx.x; b < ntb; b += gridDim.x) {
      __syncthreads();               // protect lA/lFS reuse across tiles
      do_tile(lA, tokens, TIOUF, WiouhT, WfhT, bioux, biouh, bfx, bfh,
              c16, h, h16, hin, hout, Ls, Lsz, Lup, b >> 1, b & 1);
    }
    if (l < 6) {                     // grid barrier before next level
      __threadfence();               // release: flush c16/h16/hsum to LLC
      __syncthreads();
      if (t == 0) {
        __hip_atomic_fetch_add(&ctr[l], 1, __ATOMIC_RELEASE,
                               __HIP_MEMORY_SCOPE_AGENT);
        while (__hip_atomic_load(&ctr[l], __ATOMIC_ACQUIRE,
                                 __HIP_MEMORY_SCOPE_AGENT) < (int)gridDim.x)
          __builtin_amdgcn_s_sleep(1);
      }
      __syncthreads();
      __threadfence();               // acquire: invalidate stale L1/L2
    }
  }
}

extern "C" void kernel_launch(void* const* d_in, const int* in_sizes, int n_in,
                              void* d_out, int out_size, void* d_ws, size_t ws_size,
                              hipStream_t stream) {
  const int*   tokens = (const int*)d_in[0];
  const float* emb    = (const float*)d_in[2];
  const float* Wioux  = (const float*)d_in[3];
  const float* bioux  = (const float*)d_in[4];
  const float* Wiouh  = (const float*)d_in[5];
  const float* biouh  = (const float*)d_in[6];
  const float* Wfx    = (const float*)d_in[7];
  const float* bfx    = (const float*)d_in[8];
  const float* Wfh    = (const float*)d_in[9];
  const float* bfh    = (const float*)d_in[10];
  float* h = (float*)d_out;   // fp32 h master = output [87381,256]
  (void)in_sizes; (void)n_in; (void)out_size; (void)ws_size;

  // workspace: all f16 (FH slot dead -> barrier counters; IOUH slot = hsumB)
  f16* emb_h   = (f16*)d_ws;                        //  8,192,000
  f16* BTX     = emb_h   + 8192000;                 //    262,144
  f16* WiouhT  = BTX     + 262144;                  //    196,608
  f16* WfhT    = WiouhT  + 196608;                  //     65,536
  f16* TIOUF   = WfhT    + 65536;                   // 32,768,000 (32000x1024)
  f16* hsumB   = TIOUF   + (size_t)32768000;        // (old IOUH slot)
  f16* FH_dead = hsumB   + (size_t)12582912;        // barrier ctrs live here
  f16* h16     = FH_dead + (size_t)22396928;        // 22,396,928 (87488x256)
  f16* hsumA   = h16     + (size_t)22396928;        //  4,194,304 (16384x256)
  f16* c16     = hsumA   + (size_t)4194304;         // 22,396,928 (87488x256)
  int* ctr     = (int*)FH_dead;

  // 0. convert inputs to fp16 working copies (+ zero barrier counters)
  prep<<<10049, 256, 0, stream>>>(emb, Wioux, Wfx, Wiouh, Wfh,
                                  emb_h, BTX, WiouhT, WfhT, ctr);

  // 1. vocab table: TIOUF[v] = emb[v] @ [Wioux | Wfx]  (32000x1024, 250x8 tiles)
  gemm128d<<<2000, 256, 0, stream>>>(emb_h, BTX, TIOUF, 1024, 8, 2000,
                                     emb_h, BTX, TIOUF, 1024, 8);

  // 2. leaves (65536 nodes): gates + hsumA (parents at 5461)
  elem8<<<8192, 256, 0, stream>>>(tokens, TIOUF, bioux, biouh,
                                  c16, h, h16, hsumA, 21845, 65536, 5461, 16384);

  // 3. level 1 (16384 parents): fused dual-GEMM + gates, 2048 blocks
  fused_level<<<2048, 512, 0, stream>>>(
      tokens, TIOUF, WiouhT, WfhT, bioux, biouh, bfx, bfh,
      c16, h, h16, hsumA, hsumB, 5461, 16384, 4096);

  // 4. levels 2..8: one kernel with internal grid barriers
  multi_level<<<512, 512, 0, stream>>>(
      tokens, TIOUF, WiouhT, WfhT, bioux, biouh, bfx, bfh,
      c16, h, h16, hsumA, hsumB, ctr);
}

// Round 4
// 490.993 us; speedup vs baseline: 3.3118x; 3.3118x over previous
//
#include <hip/hip_runtime.h>
#include <cstdint>
#include <cstddef>

typedef _Float16 f16;
typedef __attribute__((ext_vector_type(8))) _Float16 half8;
typedef __attribute__((ext_vector_type(4))) _Float16 half4;
typedef __attribute__((ext_vector_type(8))) short short8;
typedef __attribute__((ext_vector_type(4))) float floatx4;
typedef __attribute__((ext_vector_type(8))) float floatx8;

__device__ __forceinline__ float rcp_(float x) { return __builtin_amdgcn_rcpf(x); }
__device__ __forceinline__ float sigm(float x) { return rcp_(1.f + __expf(-x)); }
__device__ __forceinline__ float tanh_(float x) { return 1.f - 2.f * rcp_(1.f + __expf(2.f * x)); }

// Device-coherent (agent-scope, LLC) accesses: bypass the non-coherent
// per-XCD L2 so no threadfence/L2-flush is ever needed.
__device__ __forceinline__ short8 ld16_coh(const void* p) {
  unsigned long long lo = __hip_atomic_load((const unsigned long long*)p,
      __ATOMIC_RELAXED, __HIP_MEMORY_SCOPE_AGENT);
  unsigned long long hi = __hip_atomic_load((const unsigned long long*)p + 1,
      __ATOMIC_RELAXED, __HIP_MEMORY_SCOPE_AGENT);
  union { unsigned long long u[2]; short8 s; } v;
  v.u[0] = lo; v.u[1] = hi;
  return v.s;
}
__device__ __forceinline__ void st2_coh(f16* p, f16 x) {
  __hip_atomic_store((unsigned short*)p, __builtin_bit_cast(unsigned short, x),
                     __ATOMIC_RELAXED, __HIP_MEMORY_SCOPE_AGENT);
}

// Dual-job 128x128-tile GEMM: C[M,N] = A[M,256] @ BT[N,256]^T, fp16 in/out,
// fp32 accum. (Only used once, for the 32000x1024 vocab table.)
__global__ __launch_bounds__(256) void gemm128d(
    const f16* __restrict__ A0, const f16* __restrict__ B0, f16* __restrict__ C0,
    int ldc0, int nt0, int tiles0,
    const f16* __restrict__ A1, const f16* __restrict__ B1, f16* __restrict__ C1,
    int ldc1, int nt1)
{
  const f16* A; const f16* BT; f16* C; int ldc_, mi, ni;
  int bid = blockIdx.x;
  if (bid < tiles0) { A = A0; BT = B0; C = C0; ldc_ = ldc0; mi = bid / nt0; ni = bid % nt0; }
  else { int r = bid - tiles0; A = A1; BT = B1; C = C1; ldc_ = ldc1; mi = r / nt1; ni = r % nt1; }
  const int m0 = mi * 128;
  const int n0 = ni * 128;

  __shared__ short lA[128 * 72];
  __shared__ short lB[128 * 72];
  const int t = threadIdx.x;
  const int wave = t >> 6;
  const int lane = t & 63;
  const int ln = lane & 15;
  const int quad = lane >> 4;
  const int wr = wave >> 1;
  const int wc = wave & 1;

  floatx4 acc[4][4];
#pragma unroll
  for (int i = 0; i < 4; ++i)
#pragma unroll
    for (int j = 0; j < 4; ++j) acc[i][j] = (floatx4){0.f, 0.f, 0.f, 0.f};

#pragma unroll
  for (int st = 0; st < 4; ++st) {    // K = 256 in 4 stages of 64
    const int k0 = st * 64;
#pragma unroll
    for (int i = 0; i < 4; ++i) {     // 128 rows x 8 chunks of 8 halves
      int chunk = t + 256 * i;
      int row = chunk >> 3;
      int cc = chunk & 7;
      *(short8*)&lA[row * 72 + cc * 8] =
          *(const short8*)(A + (size_t)(m0 + row) * 256 + k0 + cc * 8);
      *(short8*)&lB[row * 72 + cc * 8] =
          *(const short8*)(BT + (size_t)(n0 + row) * 256 + k0 + cc * 8);
    }
    __syncthreads();
#pragma unroll
    for (int ks = 0; ks < 2; ++ks) {
      const int kk = ks * 32 + quad * 8;
      half8 a[4], b[4];
#pragma unroll
      for (int rf = 0; rf < 4; ++rf)
        a[rf] = __builtin_bit_cast(half8,
            *(const short8*)&lA[(wr * 64 + rf * 16 + ln) * 72 + kk]);
#pragma unroll
      for (int cf = 0; cf < 4; ++cf)
        b[cf] = __builtin_bit_cast(half8,
            *(const short8*)&lB[(wc * 64 + cf * 16 + ln) * 72 + kk]);
#pragma unroll
      for (int rf = 0; rf < 4; ++rf)
#pragma unroll
        for (int cf = 0; cf < 4; ++cf)
          acc[rf][cf] = __builtin_amdgcn_mfma_f32_16x16x32_f16(
              a[rf], b[cf], acc[rf][cf], 0, 0, 0);
    }
    __syncthreads();
  }
#pragma unroll
  for (int rf = 0; rf < 4; ++rf)
#pragma unroll
    for (int cf = 0; cf < 4; ++cf)
#pragma unroll
      for (int r = 0; r < 4; ++r) {
        int row = m0 + wr * 64 + rf * 16 + quad * 4 + r;
        int col = n0 + wc * 64 + cf * 16 + ln;
        C[(size_t)row * ldc_ + col] = (f16)acc[rf][cf][r];
      }
}

// fp32 inputs -> fp16 working copies; also zeroes the grid-barrier counters.
__global__ __launch_bounds__(256) void prep(
    const float* __restrict__ emb, const float* __restrict__ Wioux,
    const float* __restrict__ Wfx, const float* __restrict__ Wiouh,
    const float* __restrict__ Wfh,
    f16* __restrict__ emb_h, f16* __restrict__ BTX,
    f16* __restrict__ WiouhT, f16* __restrict__ WfhT,
    int* __restrict__ ctr)
{
  int idx = blockIdx.x * 256 + threadIdx.x;   // 10049 blocks = 2,572,544
  if (idx < 8) ctr[idx] = 0;                  // grid-barrier counters
  if (idx < 2048000) {                        // emb: 4 elems/thread
    floatx4 v = *(const floatx4*)(emb + 4 * (size_t)idx);
    half4 o;
#pragma unroll
    for (int j = 0; j < 4; ++j) o[j] = (f16)v[j];
    *(half4*)(emb_h + 4 * (size_t)idx) = o;
  } else if (idx < 2310144) {
    int r = idx - 2048000;                    // BTX[1024,256]: Wioux^T | Wfx^T
    int j = r >> 8, k = r & 255;
    BTX[r] = (f16)((j < 768) ? Wioux[(size_t)k * 768 + j]
                             : Wfx[(size_t)k * 256 + (j - 768)]);
  } else if (idx < 2506752) {
    int r = idx - 2310144;                    // WiouhT[768,256]
    int j = r >> 8, k = r & 255;
    WiouhT[r] = (f16)Wiouh[(size_t)k * 768 + j];
  } else {
    int r = idx - 2506752;                    // WfhT[256,256]
    int j = r >> 8, k = r & 255;
    WfhT[r] = (f16)Wfh[(size_t)k * 256 + j];
  }
}

// Leaf elementwise: block = 8 nodes; gates -> c16/h/h16; parent hsum16 via LDS.
__global__ __launch_bounds__(256) void elem8(
    const int* __restrict__ tokens, const f16* __restrict__ TIOUF,
    const float* __restrict__ bioux, const float* __restrict__ biouh,
    f16* __restrict__ c16, float* __restrict__ h, f16* __restrict__ h16,
    f16* __restrict__ hsum16, int s, int sz, int s_up, int sz_up)
{
  __shared__ float hsh[8 * 260];
  const int t = threadIdx.x;
  const int nloc = t >> 5;
  const int d0 = (t & 31) * 8;
  const int base = s + 8 * blockIdx.x;
  const int node = base + nloc;
  const int lim = s + sz;

  if (node < lim) {
    const f16* ti = TIOUF + (size_t)tokens[node] * 1024;
    half8 t0 = *(const half8*)(ti + d0);
    half8 t1 = *(const half8*)(ti + 256 + d0);
    half8 t2 = *(const half8*)(ti + 512 + d0);
    floatx8 bi0 = *(const floatx8*)(bioux + d0) + *(const floatx8*)(biouh + d0);
    floatx8 bi1 = *(const floatx8*)(bioux + 256 + d0) + *(const floatx8*)(biouh + 256 + d0);
    floatx8 bi2 = *(const floatx8*)(bioux + 512 + d0) + *(const floatx8*)(biouh + 512 + d0);

    float cv[8];
#pragma unroll
    for (int j = 0; j < 8; ++j)
      cv[j] = sigm((float)t0[j] + bi0[j]) * tanh_((float)t2[j] + bi2[j]);

    half8 c8, h8;
    floatx8 hf;
#pragma unroll
    for (int j = 0; j < 8; ++j) {
      float hv = sigm((float)t1[j] + bi1[j]) * tanh_(cv[j]);
      c8[j] = (f16)cv[j];
      h8[j] = (f16)hv;
      hf[j] = hv;
    }
    *(half8*)(c16 + (size_t)node * 256 + d0) = c8;
    *(floatx8*)(h + (size_t)node * 256 + d0) = hf;
    *(half8*)(h16 + (size_t)node * 256 + d0) = h8;
    *(floatx8*)&hsh[nloc * 260 + d0] = hf;
  }
  __syncthreads();

  if (t < 64) {
    int p = t >> 5;
    int dd = (t & 31) * 8;
    int parent = ((base - 1) >> 2) + p;
    if (parent < s_up + sz_up) {
      floatx8 v = *(const floatx8*)&hsh[(4 * p + 0) * 260 + dd] +
                  *(const floatx8*)&hsh[(4 * p + 1) * 260 + dd] +
                  *(const floatx8*)&hsh[(4 * p + 2) * 260 + dd] +
                  *(const floatx8*)&hsh[(4 * p + 3) * 260 + dd];
      half8 o;
#pragma unroll
      for (int j = 0; j < 8; ++j) o[j] = (f16)v[j];
      *(half8*)(hsum16 + (size_t)(parent - s_up) * 256 + dd) = o;
    }
  }
}

// One 16-parent x 128-dim tile of an internal level: dual in-register GEMM
// (IOUH via hsum_in @ WiouhT, FH via children h16 @ WfhT) + gates + stores.
// lA = 80 rows x 256 shorts, XOR-swizzled (chunk ^= row&7) = 40960 B.
// COH variant: all cross-barrier data (hsum_in, h16/c16 children, and the
// c16/h16/hsum stores) uses agent-scope relaxed atomics (sc0 sc1 -> LLC),
// so the multi-level kernel needs NO threadfence. Children c16 is staged
// into lC (stride 136 shorts -> 16B-aligned rows, mild bank aliasing).
// MFMA C layout: row-in-tile = 4*quad + reg, col = lane&15.
template <bool COH>
__device__ __forceinline__ void do_tile(
    short* lA, short* lC,
    const int* __restrict__ tokens, const f16* __restrict__ TIOUF,
    const f16* __restrict__ WiouhT, const f16* __restrict__ WfhT,
    const float* __restrict__ bioux, const float* __restrict__ biouh,
    const float* __restrict__ bfx, const float* __restrict__ bfh,
    f16* __restrict__ c16, float* __restrict__ h, f16* __restrict__ h16,
    const f16* __restrict__ hsum_in, f16* __restrict__ hsum_out,
    int s, int sz, int sz_up, int pt, int pg)
{
  const int t = threadIdx.x;
  const int p0 = s + pt * 16;        // first parent of tile
  const int c0 = 4 * p0 + 1;         // first child node (contiguous 64 rows)

  // stage A: rows 0-15 hsum(parents), 16-79 children h16; swizzled chunks
#pragma unroll
  for (int i = 0; i < 5; ++i) {
    int chunk = t + 512 * i;
    int row = chunk >> 5;
    int cc = chunk & 31;
    const f16* src = (row < 16)
        ? hsum_in + (size_t)(pt * 16 + row) * 256 + cc * 8
        : h16 + (size_t)(c0 + row - 16) * 256 + cc * 8;
    short8 v;
    if constexpr (COH) v = ld16_coh(src); else v = *(const short8*)src;
    *(short8*)&lA[row * 256 + (cc ^ (row & 7)) * 8] = v;
  }
  if constexpr (COH) {               // stage children c16 (this dim half)
#pragma unroll
    for (int i = 0; i < 2; ++i) {
      int chunk = t + 512 * i;       // 1024 chunks = 64 rows x 16
      int row = chunk >> 4;
      int cc = chunk & 15;
      short8 v = ld16_coh(c16 + (size_t)(c0 + row) * 256 + pg * 128 + cc * 8);
      *(short8*)&lC[row * 136 + cc * 8] = v;
    }
  }
  __syncthreads();

  const int wave = t >> 6;
  const int lane = t & 63;
  const int ln = lane & 15;
  const int q = lane >> 4;
  const int rb = ln & 7;
  const int dim = (pg * 8 + wave) * 16 + ln;   // 0..255
  const int dl = wave * 16 + ln;               // dim within half, 0..127

  floatx4 accI[3], accF[4];
#pragma unroll
  for (int i = 0; i < 3; ++i) accI[i] = (floatx4){0.f, 0.f, 0.f, 0.f};
#pragma unroll
  for (int i = 0; i < 4; ++i) accF[i] = (floatx4){0.f, 0.f, 0.f, 0.f};

  const short* aBase = &lA[ln * 256];
  const f16* b0p = WiouhT + (size_t)dim * 256 + 8 * q;
  const f16* b1p = b0p + 256 * 256;
  const f16* b2p = b0p + 512 * 256;
  const f16* bfp = WfhT + (size_t)dim * 256 + 8 * q;

#pragma unroll
  for (int ks = 0; ks < 8; ++ks) {   // K = 256 in 8 steps of 32
    const int ko = 32 * ks;
    const int co = ((q + 4 * ks) ^ rb) * 8;    // swizzled chunk offset
    half8 ah = __builtin_bit_cast(half8, *(const short8*)(aBase + co));
    half8 b0 = *(const half8*)(b0p + ko);
    half8 b1 = *(const half8*)(b1p + ko);
    half8 b2 = *(const half8*)(b2p + ko);
    half8 bf = *(const half8*)(bfp + ko);
    accI[0] = __builtin_amdgcn_mfma_f32_16x16x32_f16(ah, b0, accI[0], 0, 0, 0);
    accI[1] = __builtin_amdgcn_mfma_f32_16x16x32_f16(ah, b1, accI[1], 0, 0, 0);
    accI[2] = __builtin_amdgcn_mfma_f32_16x16x32_f16(ah, b2, accI[2], 0, 0, 0);
#pragma unroll
    for (int rt = 0; rt < 4; ++rt) {
      half8 ac = __builtin_bit_cast(half8,
          *(const short8*)(aBase + (16 + 16 * rt) * 256 + co));
      accF[rt] = __builtin_amdgcn_mfma_f32_16x16x32_f16(ac, bf, accF[rt], 0, 0, 0);
    }
  }
  __syncthreads();                   // all waves done with lA; overlay lFS

  float* myFS = (float*)lA + wave * (16 * 17);   // wave-private 16x17 f32

  const float bi0 = bioux[dim] + biouh[dim];
  const float bi1 = bioux[256 + dim] + biouh[256 + dim];
  const float bi2 = bioux[512 + dim] + biouh[512 + dim];
  const float bff = bfx[dim] + bfh[dim];

  // f-gates in FH layout: tile rt, reg r -> child (16rt+4q+r) of parent 4rt+q
#pragma unroll
  for (int rt = 0; rt < 4; ++rt) {
    int po = 4 * rt + q;
    int tok = tokens[p0 + po];
    float xff = (float)TIOUF[(size_t)tok * 1024 + 768 + dim] + bff;
    float fs = 0.f;
#pragma unroll
    for (int r = 0; r < 4; ++r) {
      float ccv;
      if constexpr (COH)
        ccv = (float)__builtin_bit_cast(f16, lC[(16 * rt + 4 * q + r) * 136 + dl]);
      else
        ccv = (float)c16[(size_t)(c0 + 16 * rt + 4 * q + r) * 256 + dim];
      fs += sigm(accF[rt][r] + xff) * ccv;
    }
    myFS[po * 17 + ln] = fs;
  }
  // write->read is same-wave only: drain LDS writes, pin the order
  asm volatile("s_waitcnt lgkmcnt(0)" ::: "memory");
  __builtin_amdgcn_sched_barrier(0);

  const int szrem = sz - pt * 16;
  float hsum = 0.f;
#pragma unroll
  for (int r = 0; r < 4; ++r) {      // IOUH layout: reg r -> parent 4q+r
    int po = 4 * q + r;
    const f16* tp = TIOUF + (size_t)tokens[p0 + po] * 1024;
    float iv = sigm(accI[0][r] + (float)tp[dim] + bi0);
    float ov = sigm(accI[1][r] + (float)tp[256 + dim] + bi1);
    float uv = tanh_(accI[2][r] + (float)tp[512 + dim] + bi2);
    float cn = iv * uv + myFS[po * 17 + ln];
    float hn = ov * tanh_(cn);
    hsum += hn;                      // 4 regs = 4 siblings => in-lane hsum
    if (po < szrem) {                // guard tail tiles (stores only)
      size_t pi = (size_t)(p0 + po);
      if constexpr (COH) {
        st2_coh(c16 + pi * 256 + dim, (f16)cn);
        st2_coh(h16 + pi * 256 + dim, (f16)hn);
      } else {
        c16[pi * 256 + dim] = (f16)cn;
        h16[pi * 256 + dim] = (f16)hn;
      }
      h[pi * 256 + dim] = hn;        // host-consumed: plain store is fine
    }
  }
  if (sz_up > 0) {
    int g_row = 4 * pt + q;          // next-level relative parent row
    if (g_row < sz_up) {
      if constexpr (COH)
        st2_coh(hsum_out + (size_t)g_row * 256 + dim, (f16)hsum);
      else
        hsum_out[(size_t)g_row * 256 + dim] = (f16)hsum;
    }
  }
}

// Level 1 (16384 parents): plain launch, 2048 blocks, 4 blocks/CU.
__global__ __launch_bounds__(512, 8) void fused_level(
    const int* __restrict__ tokens, const f16* __restrict__ TIOUF,
    const f16* __restrict__ WiouhT, const f16* __restrict__ WfhT,
    const float* __restrict__ bioux, const float* __restrict__ biouh,
    const float* __restrict__ bfx, const float* __restrict__ bfh,
    f16* __restrict__ c16, float* __restrict__ h, f16* __restrict__ h16,
    const f16* __restrict__ hsum_in, f16* __restrict__ hsum_out,
    int s, int sz, int sz_up)
{
  __shared__ short lA[80 * 256];     // 40960 B exactly
  do_tile<false>(lA, nullptr, tokens, TIOUF, WiouhT, WfhT, bioux, biouh,
                 bfx, bfh, c16, h, h16, hsum_in, hsum_out, s, sz, sz_up,
                 blockIdx.x >> 1, blockIdx.x & 1);
}

// Levels 2..8 in ONE kernel, 512 blocks all co-resident
// (launch_bounds(512,4) caps VGPR at 128 -> >=2 blocks/CU; LDS 58 KB -> 2).
// Cross-level sync: vmcnt(0) + relaxed agent atomic counter + sleep-spin.
// NO threadfence anywhere: all cross-barrier data moves via sc0/sc1
// (LLC-coherent) accesses inside do_tile<true>.
__global__ __launch_bounds__(512, 4) void multi_level(
    const int* __restrict__ tokens, const f16* __restrict__ TIOUF,
    const f16* __restrict__ WiouhT, const f16* __restrict__ WfhT,
    const float* __restrict__ bioux, const float* __restrict__ biouh,
    const float* __restrict__ bfx, const float* __restrict__ bfh,
    f16* __restrict__ c16, float* __restrict__ h, f16* __restrict__ h16,
    f16* __restrict__ hsumA, f16* __restrict__ hsumB, int* __restrict__ ctr)
{
  __shared__ short lA[80 * 256];
  __shared__ short lC[64 * 136];
  const int t = threadIdx.x;
  int sz = 4096;                     // level 2 .. root
#pragma unroll 1
  for (int l = 0; l < 7; ++l) {
    const int s = (sz - 1) / 3;      // tree level start
    const f16* hin = (l & 1) ? hsumA : hsumB;   // L1 wrote hsumB; alternate
    f16* hout = (l & 1) ? hsumB : hsumA;
    const int ntb = 2 * ((sz + 15) / 16);
    __syncthreads();                 // protect lA/lC reuse across levels
    if (blockIdx.x < ntb)
      do_tile<true>(lA, lC, tokens, TIOUF, WiouhT, WfhT, bioux, biouh,
                    bfx, bfh, c16, h, h16, hin, hout,
                    s, sz, (l == 6) ? 0 : (sz >> 2),
                    blockIdx.x >> 1, blockIdx.x & 1);
    if (l < 6) {                     // fence-free grid barrier
      asm volatile("s_waitcnt vmcnt(0)" ::: "memory");
      __syncthreads();
      if (t == 0) {
        __hip_atomic_fetch_add(&ctr[l], 1, __ATOMIC_RELAXED,
                               __HIP_MEMORY_SCOPE_AGENT);
        while (__hip_atomic_load(&ctr[l], __ATOMIC_RELAXED,
                                 __HIP_MEMORY_SCOPE_AGENT) < (int)gridDim.x)
          __builtin_amdgcn_s_sleep(8);
      }
      __syncthreads();
    }
    sz >>= 2;
  }
}

extern "C" void kernel_launch(void* const* d_in, const int* in_sizes, int n_in,
                              void* d_out, int out_size, void* d_ws, size_t ws_size,
                              hipStream_t stream) {
  const int*   tokens = (const int*)d_in[0];
  const float* emb    = (const float*)d_in[2];
  const float* Wioux  = (const float*)d_in[3];
  const float* bioux  = (const float*)d_in[4];
  const float* Wiouh  = (const float*)d_in[5];
  const float* biouh  = (const float*)d_in[6];
  const float* Wfx    = (const float*)d_in[7];
  const float* bfx    = (const float*)d_in[8];
  const float* Wfh    = (const float*)d_in[9];
  const float* bfh    = (const float*)d_in[10];
  float* h = (float*)d_out;   // fp32 h master = output [87381,256]
  (void)in_sizes; (void)n_in; (void)out_size; (void)ws_size;

  // workspace: all f16 (FH slot dead -> barrier counters; IOUH slot = hsumB)
  f16* emb_h   = (f16*)d_ws;                        //  8,192,000
  f16* BTX     = emb_h   + 8192000;                 //    262,144
  f16* WiouhT  = BTX     + 262144;                  //    196,608
  f16* WfhT    = WiouhT  + 196608;                  //     65,536
  f16* TIOUF   = WfhT    + 65536;                   // 32,768,000 (32000x1024)
  f16* hsumB   = TIOUF   + (size_t)32768000;        // (old IOUH slot)
  f16* FH_dead = hsumB   + (size_t)12582912;        // barrier ctrs live here
  f16* h16     = FH_dead + (size_t)22396928;        // 22,396,928 (87488x256)
  f16* hsumA   = h16     + (size_t)22396928;        //  4,194,304 (16384x256)
  f16* c16     = hsumA   + (size_t)4194304;         // 22,396,928 (87488x256)
  int* ctr     = (int*)FH_dead;

  // 0. convert inputs to fp16 working copies (+ zero barrier counters)
  prep<<<10049, 256, 0, stream>>>(emb, Wioux, Wfx, Wiouh, Wfh,
                                  emb_h, BTX, WiouhT, WfhT, ctr);

  // 1. vocab table: TIOUF[v] = emb[v] @ [Wioux | Wfx]  (32000x1024, 250x8 tiles)
  gemm128d<<<2000, 256, 0, stream>>>(emb_h, BTX, TIOUF, 1024, 8, 2000,
                                     emb_h, BTX, TIOUF, 1024, 8);

  // 2. leaves (65536 nodes): gates + hsumA (parents at 5461)
  elem8<<<8192, 256, 0, stream>>>(tokens, TIOUF, bioux, biouh,
                                  c16, h, h16, hsumA, 21845, 65536, 5461, 16384);

  // 3. level 1 (16384 parents): fused dual-GEMM + gates, 2048 blocks
  fused_level<<<2048, 512, 0, stream>>>(
      tokens, TIOUF, WiouhT, WfhT, bioux, biouh, bfx, bfh,
      c16, h, h16, hsumA, hsumB, 5461, 16384, 4096);

  // 4. levels 2..8: one kernel, fence-free internal grid barriers
  multi_level<<<512, 512, 0, stream>>>(
      tokens, TIOUF, WiouhT, WfhT, bioux, biouh, bfx, bfh,
      c16, h, h16, hsumA, hsumB, ctr);
}

// Round 5
// 415.908 us; speedup vs baseline: 3.9097x; 1.1805x over previous
//
#include <hip/hip_runtime.h>
#include <cstdint>
#include <cstddef>

typedef _Float16 f16;
typedef __attribute__((ext_vector_type(8))) _Float16 half8;
typedef __attribute__((ext_vector_type(4))) _Float16 half4;
typedef __attribute__((ext_vector_type(8))) short short8;
typedef __attribute__((ext_vector_type(4))) float floatx4;
typedef __attribute__((ext_vector_type(8))) float floatx8;

__device__ __forceinline__ float rcp_(float x) { return __builtin_amdgcn_rcpf(x); }
__device__ __forceinline__ float sigm(float x) { return rcp_(1.f + __expf(-x)); }
__device__ __forceinline__ float tanh_(float x) { return 1.f - 2.f * rcp_(1.f + __expf(2.f * x)); }

// Device-coherent (agent-scope, LLC) accesses — used ONLY in the tiny tail
// kernel where cross-block coherence without fences is needed.
__device__ __forceinline__ short8 ld16_coh(const void* p) {
  unsigned long long lo = __hip_atomic_load((const unsigned long long*)p,
      __ATOMIC_RELAXED, __HIP_MEMORY_SCOPE_AGENT);
  unsigned long long hi = __hip_atomic_load((const unsigned long long*)p + 1,
      __ATOMIC_RELAXED, __HIP_MEMORY_SCOPE_AGENT);
  union { unsigned long long u[2]; short8 s; } v;
  v.u[0] = lo; v.u[1] = hi;
  return v.s;
}
__device__ __forceinline__ void st2_coh(f16* p, f16 x) {
  __hip_atomic_store((unsigned short*)p, __builtin_bit_cast(unsigned short, x),
                     __ATOMIC_RELAXED, __HIP_MEMORY_SCOPE_AGENT);
}

// Dual-job 128x128-tile GEMM: C[M,N] = A[M,256] @ BT[N,256]^T, fp16 in/out,
// fp32 accum. (Only used once, for the 32000x1024 vocab table.)
// XCD swizzle: the 8 column-tiles sharing one A row-tile are consecutive
// logical tiles; remap so they land on ONE XCD -> A re-reads hit L2.
__global__ __launch_bounds__(256) void gemm128d(
    const f16* __restrict__ A0, const f16* __restrict__ B0, f16* __restrict__ C0,
    int ldc0, int nt0, int tiles0,
    const f16* __restrict__ A1, const f16* __restrict__ B1, f16* __restrict__ C1,
    int ldc1, int nt1)
{
  const f16* A; const f16* BT; f16* C; int ldc_, mi, ni;
  int bid = blockIdx.x;
  bid = (bid & 7) * ((int)gridDim.x >> 3) + (bid >> 3);   // grid % 8 == 0
  if (bid < tiles0) { A = A0; BT = B0; C = C0; ldc_ = ldc0; mi = bid / nt0; ni = bid % nt0; }
  else { int r = bid - tiles0; A = A1; BT = B1; C = C1; ldc_ = ldc1; mi = r / nt1; ni = r % nt1; }
  const int m0 = mi * 128;
  const int n0 = ni * 128;

  __shared__ short lA[128 * 72];
  __shared__ short lB[128 * 72];
  const int t = threadIdx.x;
  const int wave = t >> 6;
  const int lane = t & 63;
  const int ln = lane & 15;
  const int quad = lane >> 4;
  const int wr = wave >> 1;
  const int wc = wave & 1;

  floatx4 acc[4][4];
#pragma unroll
  for (int i = 0; i < 4; ++i)
#pragma unroll
    for (int j = 0; j < 4; ++j) acc[i][j] = (floatx4){0.f, 0.f, 0.f, 0.f};

#pragma unroll
  for (int st = 0; st < 4; ++st) {    // K = 256 in 4 stages of 64
    const int k0 = st * 64;
#pragma unroll
    for (int i = 0; i < 4; ++i) {     // 128 rows x 8 chunks of 8 halves
      int chunk = t + 256 * i;
      int row = chunk >> 3;
      int cc = chunk & 7;
      *(short8*)&lA[row * 72 + cc * 8] =
          *(const short8*)(A + (size_t)(m0 + row) * 256 + k0 + cc * 8);
      *(short8*)&lB[row * 72 + cc * 8] =
          *(const short8*)(BT + (size_t)(n0 + row) * 256 + k0 + cc * 8);
    }
    __syncthreads();
#pragma unroll
    for (int ks = 0; ks < 2; ++ks) {
      const int kk = ks * 32 + quad * 8;
      half8 a[4], b[4];
#pragma unroll
      for (int rf = 0; rf < 4; ++rf)
        a[rf] = __builtin_bit_cast(half8,
            *(const short8*)&lA[(wr * 64 + rf * 16 + ln) * 72 + kk]);
#pragma unroll
      for (int cf = 0; cf < 4; ++cf)
        b[cf] = __builtin_bit_cast(half8,
            *(const short8*)&lB[(wc * 64 + cf * 16 + ln) * 72 + kk]);
#pragma unroll
      for (int rf = 0; rf < 4; ++rf)
#pragma unroll
        for (int cf = 0; cf < 4; ++cf)
          acc[rf][cf] = __builtin_amdgcn_mfma_f32_16x16x32_f16(
              a[rf], b[cf], acc[rf][cf], 0, 0, 0);
    }
    __syncthreads();
  }
#pragma unroll
  for (int rf = 0; rf < 4; ++rf)
#pragma unroll
    for (int cf = 0; cf < 4; ++cf)
#pragma unroll
      for (int r = 0; r < 4; ++r) {
        int row = m0 + wr * 64 + rf * 16 + quad * 4 + r;
        int col = n0 + wc * 64 + cf * 16 + ln;
        C[(size_t)row * ldc_ + col] = (f16)acc[rf][cf][r];
      }
}

// fp32 inputs -> fp16 working copies; also zeroes the tail barrier counters.
__global__ __launch_bounds__(256) void prep(
    const float* __restrict__ emb, const float* __restrict__ Wioux,
    const float* __restrict__ Wfx, const float* __restrict__ Wiouh,
    const float* __restrict__ Wfh,
    f16* __restrict__ emb_h, f16* __restrict__ BTX,
    f16* __restrict__ WiouhT, f16* __restrict__ WfhT,
    int* __restrict__ ctr)
{
  int idx = blockIdx.x * 256 + threadIdx.x;   // 10049 blocks = 2,572,544
  if (idx < 8) ctr[idx] = 0;                  // tail barrier counters
  if (idx < 2048000) {                        // emb: 4 elems/thread
    floatx4 v = *(const floatx4*)(emb + 4 * (size_t)idx);
    half4 o;
#pragma unroll
    for (int j = 0; j < 4; ++j) o[j] = (f16)v[j];
    *(half4*)(emb_h + 4 * (size_t)idx) = o;
  } else if (idx < 2310144) {
    int r = idx - 2048000;                    // BTX[1024,256]: Wioux^T | Wfx^T
    int j = r >> 8, k = r & 255;
    BTX[r] = (f16)((j < 768) ? Wioux[(size_t)k * 768 + j]
                             : Wfx[(size_t)k * 256 + (j - 768)]);
  } else if (idx < 2506752) {
    int r = idx - 2310144;                    // WiouhT[768,256]
    int j = r >> 8, k = r & 255;
    WiouhT[r] = (f16)Wiouh[(size_t)k * 768 + j];
  } else {
    int r = idx - 2506752;                    // WfhT[256,256]
    int j = r >> 8, k = r & 255;
    WfhT[r] = (f16)Wfh[(size_t)k * 256 + j];
  }
}

// Leaf elementwise: block = 8 nodes; gates -> c16/h/h16; parent hsum16 via LDS.
__global__ __launch_bounds__(256) void elem8(
    const int* __restrict__ tokens, const f16* __restrict__ TIOUF,
    const float* __restrict__ bioux, const float* __restrict__ biouh,
    f16* __restrict__ c16, float* __restrict__ h, f16* __restrict__ h16,
    f16* __restrict__ hsum16, int s, int sz, int s_up, int sz_up)
{
  __shared__ float hsh[8 * 260];
  const int t = threadIdx.x;
  const int nloc = t >> 5;
  const int d0 = (t & 31) * 8;
  const int base = s + 8 * blockIdx.x;
  const int node = base + nloc;
  const int lim = s + sz;

  if (node < lim) {
    const f16* ti = TIOUF + (size_t)tokens[node] * 1024;
    half8 t0 = *(const half8*)(ti + d0);
    half8 t1 = *(const half8*)(ti + 256 + d0);
    half8 t2 = *(const half8*)(ti + 512 + d0);
    floatx8 bi0 = *(const floatx8*)(bioux + d0) + *(const floatx8*)(biouh + d0);
    floatx8 bi1 = *(const floatx8*)(bioux + 256 + d0) + *(const floatx8*)(biouh + 256 + d0);
    floatx8 bi2 = *(const floatx8*)(bioux + 512 + d0) + *(const floatx8*)(biouh + 512 + d0);

    float cv[8];
#pragma unroll
    for (int j = 0; j < 8; ++j)
      cv[j] = sigm((float)t0[j] + bi0[j]) * tanh_((float)t2[j] + bi2[j]);

    half8 c8, h8;
    floatx8 hf;
#pragma unroll
    for (int j = 0; j < 8; ++j) {
      float hv = sigm((float)t1[j] + bi1[j]) * tanh_(cv[j]);
      c8[j] = (f16)cv[j];
      h8[j] = (f16)hv;
      hf[j] = hv;
    }
    *(half8*)(c16 + (size_t)node * 256 + d0) = c8;
    *(floatx8*)(h + (size_t)node * 256 + d0) = hf;
    *(half8*)(h16 + (size_t)node * 256 + d0) = h8;
    *(floatx8*)&hsh[nloc * 260 + d0] = hf;
  }
  __syncthreads();

  if (t < 64) {
    int p = t >> 5;
    int dd = (t & 31) * 8;
    int parent = ((base - 1) >> 2) + p;
    if (parent < s_up + sz_up) {
      floatx8 v = *(const floatx8*)&hsh[(4 * p + 0) * 260 + dd] +
                  *(const floatx8*)&hsh[(4 * p + 1) * 260 + dd] +
                  *(const floatx8*)&hsh[(4 * p + 2) * 260 + dd] +
                  *(const floatx8*)&hsh[(4 * p + 3) * 260 + dd];
      half8 o;
#pragma unroll
      for (int j = 0; j < 8; ++j) o[j] = (f16)v[j];
      *(half8*)(hsum16 + (size_t)(parent - s_up) * 256 + dd) = o;
    }
  }
}

// One 16-parent x 128-dim half-tile of an internal level: dual in-register
// GEMM (IOUH via hsum_in @ WiouhT, FH via children h16 @ WfhT) + gates.
// lA = 80 rows x 256 shorts, XOR-swizzled (chunk ^= row&7) = 40960 B.
// COH=true (tail kernel only): cross-barrier data via LLC-coherent accesses;
// children c16 staged into lC. MFMA C layout: row = 4*quad+reg, col = lane&15.
template <bool COH>
__device__ __forceinline__ void do_tile(
    short* lA, short* lC,
    const int* __restrict__ tokens, const f16* __restrict__ TIOUF,
    const f16* __restrict__ WiouhT, const f16* __restrict__ WfhT,
    const float* __restrict__ bioux, const float* __restrict__ biouh,
    const float* __restrict__ bfx, const float* __restrict__ bfh,
    f16* __restrict__ c16, float* __restrict__ h, f16* __restrict__ h16,
    const f16* __restrict__ hsum_in, f16* __restrict__ hsum_out,
    int s, int sz, int sz_up, int pt, int pg)
{
  const int t = threadIdx.x;
  const int p0 = s + pt * 16;        // first parent of tile
  const int c0 = 4 * p0 + 1;         // first child node (contiguous 64 rows)

  // stage A: rows 0-15 hsum(parents), 16-79 children h16; swizzled chunks
#pragma unroll
  for (int i = 0; i < 5; ++i) {
    int chunk = t + 512 * i;
    int row = chunk >> 5;
    int cc = chunk & 31;
    const f16* src = (row < 16)
        ? hsum_in + (size_t)(pt * 16 + row) * 256 + cc * 8
        : h16 + (size_t)(c0 + row - 16) * 256 + cc * 8;
    short8 v;
    if constexpr (COH) v = ld16_coh(src); else v = *(const short8*)src;
    *(short8*)&lA[row * 256 + (cc ^ (row & 7)) * 8] = v;
  }
  if constexpr (COH) {               // stage children c16 (this dim half)
#pragma unroll
    for (int i = 0; i < 2; ++i) {
      int chunk = t + 512 * i;       // 1024 chunks = 64 rows x 16
      int row = chunk >> 4;
      int cc = chunk & 15;
      short8 v = ld16_coh(c16 + (size_t)(c0 + row) * 256 + pg * 128 + cc * 8);
      *(short8*)&lC[row * 136 + cc * 8] = v;
    }
  }
  __syncthreads();

  const int wave = t >> 6;
  const int lane = t & 63;
  const int ln = lane & 15;
  const int q = lane >> 4;
  const int rb = ln & 7;
  const int dim = (pg * 8 + wave) * 16 + ln;   // 0..255
  const int dl = wave * 16 + ln;               // dim within half, 0..127

  floatx4 accI[3], accF[4];
#pragma unroll
  for (int i = 0; i < 3; ++i) accI[i] = (floatx4){0.f, 0.f, 0.f, 0.f};
#pragma unroll
  for (int i = 0; i < 4; ++i) accF[i] = (floatx4){0.f, 0.f, 0.f, 0.f};

  const short* aBase = &lA[ln * 256];
  const f16* b0p = WiouhT + (size_t)dim * 256 + 8 * q;
  const f16* b1p = b0p + 256 * 256;
  const f16* b2p = b0p + 512 * 256;
  const f16* bfp = WfhT + (size_t)dim * 256 + 8 * q;

#pragma unroll
  for (int ks = 0; ks < 8; ++ks) {   // K = 256 in 8 steps of 32
    const int ko = 32 * ks;
    const int co = ((q + 4 * ks) ^ rb) * 8;    // swizzled chunk offset
    half8 ah = __builtin_bit_cast(half8, *(const short8*)(aBase + co));
    half8 b0 = *(const half8*)(b0p + ko);
    half8 b1 = *(const half8*)(b1p + ko);
    half8 b2 = *(const half8*)(b2p + ko);
    half8 bf = *(const half8*)(bfp + ko);
    accI[0] = __builtin_amdgcn_mfma_f32_16x16x32_f16(ah, b0, accI[0], 0, 0, 0);
    accI[1] = __builtin_amdgcn_mfma_f32_16x16x32_f16(ah, b1, accI[1], 0, 0, 0);
    accI[2] = __builtin_amdgcn_mfma_f32_16x16x32_f16(ah, b2, accI[2], 0, 0, 0);
#pragma unroll
    for (int rt = 0; rt < 4; ++rt) {
      half8 ac = __builtin_bit_cast(half8,
          *(const short8*)(aBase + (16 + 16 * rt) * 256 + co));
      accF[rt] = __builtin_amdgcn_mfma_f32_16x16x32_f16(ac, bf, accF[rt], 0, 0, 0);
    }
  }
  __syncthreads();                   // all waves done with lA; overlay lFS

  float* myFS = (float*)lA + wave * (16 * 17);   // wave-private 16x17 f32

  const float bi0 = bioux[dim] + biouh[dim];
  const float bi1 = bioux[256 + dim] + biouh[256 + dim];
  const float bi2 = bioux[512 + dim] + biouh[512 + dim];
  const float bff = bfx[dim] + bfh[dim];

  // f-gates in FH layout: tile rt, reg r -> child (16rt+4q+r) of parent 4rt+q
#pragma unroll
  for (int rt = 0; rt < 4; ++rt) {
    int po = 4 * rt + q;
    int tok = tokens[p0 + po];
    float xff = (float)TIOUF[(size_t)tok * 1024 + 768 + dim] + bff;
    float fs = 0.f;
#pragma unroll
    for (int r = 0; r < 4; ++r) {
      float ccv;
      if constexpr (COH)
        ccv = (float)__builtin_bit_cast(f16, lC[(16 * rt + 4 * q + r) * 136 + dl]);
      else
        ccv = (float)c16[(size_t)(c0 + 16 * rt + 4 * q + r) * 256 + dim];
      fs += sigm(accF[rt][r] + xff) * ccv;
    }
    myFS[po * 17 + ln] = fs;
  }
  // write->read is same-wave only: drain LDS writes, pin the order
  asm volatile("s_waitcnt lgkmcnt(0)" ::: "memory");
  __builtin_amdgcn_sched_barrier(0);

  const int szrem = sz - pt * 16;
  float hsum = 0.f;
#pragma unroll
  for (int r = 0; r < 4; ++r) {      // IOUH layout: reg r -> parent 4q+r
    int po = 4 * q + r;
    const f16* tp = TIOUF + (size_t)tokens[p0 + po] * 1024;
    float iv = sigm(accI[0][r] + (float)tp[dim] + bi0);
    float ov = sigm(accI[1][r] + (float)tp[256 + dim] + bi1);
    float uv = tanh_(accI[2][r] + (float)tp[512 + dim] + bi2);
    float cn = iv * uv + myFS[po * 17 + ln];
    float hn = ov * tanh_(cn);
    hsum += hn;                      // 4 regs = 4 siblings => in-lane hsum
    if (po < szrem) {                // guard tail tiles (stores only)
      size_t pi = (size_t)(p0 + po);
      if constexpr (COH) {
        st2_coh(c16 + pi * 256 + dim, (f16)cn);
        st2_coh(h16 + pi * 256 + dim, (f16)hn);
      } else {
        c16[pi * 256 + dim] = (f16)cn;
        h16[pi * 256 + dim] = (f16)hn;
      }
      h[pi * 256 + dim] = hn;        // host-consumed: plain store is fine
    }
  }
  if (sz_up > 0) {
    int g_row = 4 * pt + q;          // next-level relative parent row
    if (g_row < sz_up) {
      if constexpr (COH)
        st2_coh(hsum_out + (size_t)g_row * 256 + dim, (f16)hsum);
      else
        hsum_out[(size_t)g_row * 256 + dim] = (f16)hsum;
    }
  }
}

// Internal levels sz>=64: one block per (tile, dim-half). XCD pair-swizzle:
// the two halves of a tile (and consecutive tiles) land on the SAME XCD so
// the duplicated A-stage / c16 gathers hit that XCD's L2 instead of HBM.
// 40960 B LDS + VGPR<=64 -> 4 blocks/CU.
__global__ __launch_bounds__(512, 8) void fused_level(
    const int* __restrict__ tokens, const f16* __restrict__ TIOUF,
    const f16* __restrict__ WiouhT, const f16* __restrict__ WfhT,
    const float* __restrict__ bioux, const float* __restrict__ biouh,
    const float* __restrict__ bfx, const float* __restrict__ bfh,
    f16* __restrict__ c16, float* __restrict__ h, f16* __restrict__ h16,
    const f16* __restrict__ hsum_in, f16* __restrict__ hsum_out,
    int s, int sz, int sz_up)
{
  __shared__ short lA[80 * 256];     // 40960 B exactly
  int b = blockIdx.x;                // gridDim.x % 8 == 0 for all our levels
  int lb = (b & 7) * ((int)gridDim.x >> 3) + (b >> 3);
  do_tile<false>(lA, nullptr, tokens, TIOUF, WiouhT, WfhT, bioux, biouh,
                 bfx, bfh, c16, h, h16, hsum_in, hsum_out, s, sz, sz_up,
                 lb >> 1, lb & 1);
}

// Tail: levels sz=16,4,1 in ONE kernel, 2 blocks (one per dim half), each
// level one tile. Cross-level/block data via LLC-coherent accesses; barrier
// = vmcnt(0) + relaxed agent atomic (2 blocks trivially co-resident).
__global__ __launch_bounds__(512, 4) void tail3(
    const int* __restrict__ tokens, const f16* __restrict__ TIOUF,
    const f16* __restrict__ WiouhT, const f16* __restrict__ WfhT,
    const float* __restrict__ bioux, const float* __restrict__ biouh,
    const float* __restrict__ bfx, const float* __restrict__ bfh,
    f16* __restrict__ c16, float* __restrict__ h, f16* __restrict__ h16,
    f16* __restrict__ hsumA, f16* __restrict__ hsumB, int* __restrict__ ctr)
{
  __shared__ short lA[80 * 256];
  __shared__ short lC[64 * 136];
  const int pg = blockIdx.x;         // 0 / 1
#pragma unroll 1
  for (int l = 0; l < 3; ++l) {
    const int s  = (l == 0) ? 5 : (l == 1) ? 1 : 0;
    const int sz = (l == 0) ? 16 : (l == 1) ? 4 : 1;
    const int up = (l == 0) ? 4 : (l == 1) ? 1 : 0;
    const f16* hin = (l == 1) ? hsumA : hsumB;   // B, A, B (L5 wrote B)
    f16* hout = (l == 0) ? hsumA : (l == 1) ? hsumB : nullptr;
    __syncthreads();                 // protect lA/lC reuse across levels
    do_tile<true>(lA, lC, tokens, TIOUF, WiouhT, WfhT, bioux, biouh,
                  bfx, bfh, c16, h, h16, hin, hout, s, sz, up, 0, pg);
    if (l < 2) {
      asm volatile("s_waitcnt vmcnt(0)" ::: "memory");
      __syncthreads();
      if (threadIdx.x == 0) {
        __hip_atomic_fetch_add(&ctr[l], 1, __ATOMIC_RELAXED,
                               __HIP_MEMORY_SCOPE_AGENT);
        while (__hip_atomic_load(&ctr[l], __ATOMIC_RELAXED,
                                 __HIP_MEMORY_SCOPE_AGENT) < 2)
          __builtin_amdgcn_s_sleep(1);
      }
      __syncthreads();
    }
  }
}

extern "C" void kernel_launch(void* const* d_in, const int* in_sizes, int n_in,
                              void* d_out, int out_size, void* d_ws, size_t ws_size,
                              hipStream_t stream) {
  const int*   tokens = (const int*)d_in[0];
  const float* emb    = (const float*)d_in[2];
  const float* Wioux  = (const float*)d_in[3];
  const float* bioux  = (const float*)d_in[4];
  const float* Wiouh  = (const float*)d_in[5];
  const float* biouh  = (const float*)d_in[6];
  const float* Wfx    = (const float*)d_in[7];
  const float* bfx    = (const float*)d_in[8];
  const float* Wfh    = (const float*)d_in[9];
  const float* bfh    = (const float*)d_in[10];
  float* h = (float*)d_out;   // fp32 h master = output [87381,256]
  (void)in_sizes; (void)n_in; (void)out_size; (void)ws_size;

  // workspace: all f16 (FH slot dead -> barrier counters; IOUH slot = hsumB)
  f16* emb_h   = (f16*)d_ws;                        //  8,192,000
  f16* BTX     = emb_h   + 8192000;                 //    262,144
  f16* WiouhT  = BTX     + 262144;                  //    196,608
  f16* WfhT    = WiouhT  + 196608;                  //     65,536
  f16* TIOUF   = WfhT    + 65536;                   // 32,768,000 (32000x1024)
  f16* hsumB   = TIOUF   + (size_t)32768000;        // (old IOUH slot)
  f16* FH_dead = hsumB   + (size_t)12582912;        // barrier ctrs live here
  f16* h16     = FH_dead + (size_t)22396928;        // 22,396,928 (87488x256)
  f16* hsumA   = h16     + (size_t)22396928;        //  4,194,304 (16384x256)
  f16* c16     = hsumA   + (size_t)4194304;         // 22,396,928 (87488x256)
  int* ctr     = (int*)FH_dead;

  // 0. convert inputs to fp16 working copies (+ zero barrier counters)
  prep<<<10049, 256, 0, stream>>>(emb, Wioux, Wfx, Wiouh, Wfh,
                                  emb_h, BTX, WiouhT, WfhT, ctr);

  // 1. vocab table: TIOUF[v] = emb[v] @ [Wioux | Wfx]  (32000x1024, 250x8 tiles)
  gemm128d<<<2000, 256, 0, stream>>>(emb_h, BTX, TIOUF, 1024, 8, 2000,
                                     emb_h, BTX, TIOUF, 1024, 8);

  // 2. leaves (65536 nodes): gates + hsumA (parents at 5461)
  elem8<<<8192, 256, 0, stream>>>(tokens, TIOUF, bioux, biouh,
                                  c16, h, h16, hsumA, 21845, 65536, 5461, 16384);

  // 3. levels 1..5 (sz 16384,4096,1024,256,64): fused dual-GEMM + gates
  const int LV[5][3] = {{5461, 16384, 4096}, {1365, 4096, 1024},
                        {341, 1024, 256},    {85, 256, 64}, {21, 64, 16}};
  for (int i = 0; i < 5; ++i) {
    int s = LV[i][0], sz = LV[i][1], up = LV[i][2];
    const f16* hin = (i & 1) ? hsumB : hsumA;   // elem8 wrote hsumA
    f16* hout = (i & 1) ? hsumA : hsumB;
    int blocks = 2 * ((sz + 15) / 16);
    fused_level<<<blocks, 512, 0, stream>>>(
        tokens, TIOUF, WiouhT, WfhT, bioux, biouh, bfx, bfh,
        c16, h, h16, hin, hout, s, sz, up);
  }

  // 4. levels sz=16,4,1: one 2-block kernel (L5 wrote hsumB)
  tail3<<<2, 512, 0, stream>>>(
      tokens, TIOUF, WiouhT, WfhT, bioux, biouh, bfx, bfh,
      c16, h, h16, hsumA, hsumB, ctr);
}